// Round 5
// baseline (89.199 us; speedup 1.0000x reference)
//
#include <hip/hip_runtime.h>
#include <hip/hip_bf16.h>

#define N_ROWS 8192
#define DIMS 64
#define MARGIN 1.1f
#define EPS 1e-8f
#define TILE 128
#define NB 64                       // 64 row-tiles of 128
#define NPAIRS (NB * (NB + 1) / 2)  // 2080 upper-triangle tile pairs

typedef __bf16 bf16x8 __attribute__((ext_vector_type(8)));
typedef float f32x4 __attribute__((ext_vector_type(4)));

// ---------------- Kernel 1: row-normalize, f32 -> bf16 ----------------------
// lane handles (row = t>>4, cols 4*(t&15)..+3): float4 load, 4-shfl reduce.
__global__ __launch_bounds__(256) void normalize_kernel(const float* __restrict__ x,
                                                        __bf16* __restrict__ xn) {
    const int t   = blockIdx.x * 256 + threadIdx.x;
    const int row = t >> 4;
    const int c0  = (t & 15) * 4;
    float4 v = *(const float4*)(x + row * DIMS + c0);
    float sq = v.x * v.x + v.y * v.y + v.z * v.z + v.w * v.w;
    sq += __shfl_xor(sq, 1);
    sq += __shfl_xor(sq, 2);
    sq += __shfl_xor(sq, 4);
    sq += __shfl_xor(sq, 8);
    float s = 1.f / fmaxf(sqrtf(sq), EPS);
    union { ushort4 u; __bf16 h[4]; } o;
    o.h[0] = (__bf16)(v.x * s);
    o.h[1] = (__bf16)(v.y * s);
    o.h[2] = (__bf16)(v.z * s);
    o.h[3] = (__bf16)(v.w * s);
    *(ushort4*)(xn + row * DIMS + c0) = o.u;
}

// ---------------- Kernel 2: Gram + hinge, no LDS, no barriers ---------------
// One 128x128 tile-pair per block; 2x2 waves each own a 64x64 sub-tile.
// Fragments loaded straight from global (xn is L2/L3-resident) into VGPRs;
// every wave is fully independent — latency hidden by 12 waves/CU of MLP.
__global__ __launch_bounds__(256, 3) void gram_loss_kernel(const __bf16* __restrict__ xn,
                                                           const int* __restrict__ cm,
                                                           float* __restrict__ partials) {
    const int t    = threadIdx.x;
    const int lane = t & 63;
    const int wid  = t >> 6;
    const int wr   = wid >> 1;     // 2x2 waves, each owns a 64x64 output
    const int wc   = wid & 1;
    const int frow = lane & 15;
    const int quad = lane >> 4;

    // closed-form triangular decode (float guess + integer fixup)
    const int p = blockIdx.x;
    int bi = (int)(((2.f * NB + 1.f) -
                    sqrtf((2.f * NB + 1.f) * (2.f * NB + 1.f) - 8.f * (float)p)) * 0.5f);
    while ((bi + 1) * (2 * NB - bi) / 2 <= p) ++bi;
    while (bi * (2 * NB - bi + 1) / 2 > p) --bi;
    const int bj = bi + (p - bi * (2 * NB - bi + 1) / 2);

    // MFMA 16x16x32 bf16 input layout: lane holds row (frow) x k-slice (quad*8..+7)
    // -> byte address = row*128 + quad*16 (+ kk*64 for the second K-half).
    const char* Abase = (const char*)xn + ((size_t)bi * TILE + wr * 64 + frow) * 128 + quad * 16;
    const char* Bbase = (const char*)xn + ((size_t)bj * TILE + wc * 64 + frow) * 128 + quad * 16;

    bf16x8 a[2][4], b[2][4];
    #pragma unroll
    for (int kk = 0; kk < 2; ++kk)
        #pragma unroll
        for (int m = 0; m < 4; ++m) {
            a[kk][m] = *(const bf16x8*)(Abase + m * (16 * 128) + kk * 64);
            b[kk][m] = *(const bf16x8*)(Bbase + m * (16 * 128) + kk * 64);
        }

    f32x4 acc4[4][4];
    #pragma unroll
    for (int m = 0; m < 4; ++m)
        #pragma unroll
        for (int n = 0; n < 4; ++n)
            acc4[m][n] = (f32x4){0.f, 0.f, 0.f, 0.f};

    #pragma unroll
    for (int kk = 0; kk < 2; ++kk)
        #pragma unroll
        for (int m = 0; m < 4; ++m)
            #pragma unroll
            for (int n = 0; n < 4; ++n)
                acc4[m][n] = __builtin_amdgcn_mfma_f32_16x16x32_bf16(a[kk][m], b[kk][n], acc4[m][n], 0, 0, 0);

    // labels loaded after MFMA issue (L1/L2-hot; keeps peak VGPR down)
    int4 ca4[4];
    #pragma unroll
    for (int m = 0; m < 4; ++m)
        ca4[m] = *(const int4*)(cm + bi * TILE + wr * 64 + m * 16 + quad * 4);
    int cb[4];
    #pragma unroll
    for (int n = 0; n < 4; ++n)
        cb[n] = cm[bj * TILE + wc * 64 + n * 16 + frow];

    // hinge epilogue; C/D layout: col = lane&15, row = (lane>>4)*4 + reg.
    // same-class contribution (1-c) split as (-c) on VALU + count on SALU:
    // psum += eq ? -c : max(c+0.1, 0);  eqc += popc(ballot(eq))  [wave-uniform]
    float psum = 0.f;
    unsigned eqc = 0;
    #pragma unroll
    for (int m = 0; m < 4; ++m) {
        int car[4] = {ca4[m].x, ca4[m].y, ca4[m].z, ca4[m].w};
        #pragma unroll
        for (int n = 0; n < 4; ++n) {
            #pragma unroll
            for (int r = 0; r < 4; ++r) {
                float c = acc4[m][n][r];
                bool eq = (car[r] == cb[n]);
                eqc += (unsigned)__popcll(__ballot(eq));
                float h = fmaxf(c + (MARGIN - 1.f), 0.f);
                psum += eq ? -c : h;
            }
        }
    }

    #pragma unroll
    for (int off = 32; off; off >>= 1) psum += __shfl_xor(psum, off);
    if (lane == 0) {
        float tot = psum + (float)eqc;             // + N_eq * 1.0
        partials[p * 4 + wid] = (bi != bj) ? 2.f * tot : tot;
    }
}

// ---------------- Kernel 3: finalize (sum 4*NPAIRS per-wave partials) -------
__global__ __launch_bounds__(256) void finalize_kernel(const float* __restrict__ partials,
                                                       float* __restrict__ out) {
    const int lane = threadIdx.x & 63;
    const int wid  = threadIdx.x >> 6;
    float s = 0.f;
    for (int i = threadIdx.x; i < 4 * NPAIRS; i += 256) s += partials[i];
    #pragma unroll
    for (int off = 32; off; off >>= 1) s += __shfl_xor(s, off);
    __shared__ float red[4];
    if (lane == 0) red[wid] = s;
    __syncthreads();
    if (threadIdx.x == 0)
        out[0] = (red[0] + red[1] + red[2] + red[3]) *
                 (1.f / ((float)N_ROWS * (float)N_ROWS));
}

extern "C" void kernel_launch(void* const* d_in, const int* in_sizes, int n_in,
                              void* d_out, int out_size, void* d_ws, size_t ws_size,
                              hipStream_t stream) {
    const float* bottleneck = (const float*)d_in[0];
    const int*   class_map  = (const int*)d_in[1];
    float* out = (float*)d_out;

    float*  partials = (float*)d_ws;                    // 8320 floats
    __bf16* xnw      = (__bf16*)((char*)d_ws + 65536);  // 1 MB normalized bf16

    normalize_kernel<<<512, 256, 0, stream>>>(bottleneck, xnw);
    gram_loss_kernel<<<NPAIRS, 256, 0, stream>>>(xnw, class_map, partials);
    finalize_kernel<<<1, 256, 0, stream>>>(partials, out);
}